// Round 13
// baseline (106.543 us; speedup 1.0000x reference)
//
#include <hip/hip_runtime.h>
#include <hip/hip_bf16.h>

typedef __attribute__((ext_vector_type(8))) short short8;
typedef __attribute__((ext_vector_type(4))) float f32x4;

#define N_U 8192
#define N_I 8192
#define KD  256

// ws float-slot layout: [0,8192) gemm err (1024 blocks x 8 waves);
// [8192,8704) pack_a; [8704,10752) pack_v. All written unconditionally.
#define ERR_SLOTS 8192
#define REGA_BASE 8192
#define REGV_BASE 8704
#define SLOTS_END 10752

// global_load_lds, 16B per lane.
#define GLD16(g, l) __builtin_amdgcn_global_load_lds( \
    (const __attribute__((address_space(1))) unsigned int*)(unsigned long long)(uintptr_t)(g), \
    (__attribute__((address_space(3))) unsigned int*)(unsigned int)(uintptr_t)(l), 16, 0, 0)

static __device__ __forceinline__ unsigned short f2bf(float x) {
  unsigned u = __builtin_bit_cast(unsigned, x);
  u += 0x7fffu + ((u >> 16) & 1u);   // round-to-nearest-even
  return (unsigned short)(u >> 16);
}

static __device__ __forceinline__ void block_reduce_store(float v, float* slot) {
  #pragma unroll
  for (int off = 32; off > 0; off >>= 1) v += __shfl_down(v, off, 64);
  __shared__ float red[4];
  int lane = threadIdx.x & 63, wv = threadIdx.x >> 6;
  if (lane == 0) red[wv] = v;
  __syncthreads();
  if (threadIdx.x == 0) *slot = red[0] + red[1] + red[2] + red[3];
}

// A = P.T (elementwise*) U  -> bf16 [N_U][KD]; partial sum(U^2)+sum(P^2) to slot.
__global__ __launch_bounds__(256) void pack_a_kernel(
    const float* __restrict__ U, const float* __restrict__ P,
    unsigned short* __restrict__ Abf, float* __restrict__ ws)
{
  __shared__ float Pt[64][65];   // +1 pad
  const int u0 = blockIdx.x * 64;
  const int k0 = blockIdx.y * 64;
  const int t = threadIdx.x;
  float ss = 0.f;
  {
    const int ul4 = (t & 15) * 4, klb = t >> 4;
    #pragma unroll
    for (int pass = 0; pass < 4; ++pass) {
      int kl = klb + pass * 16;
      float4 pv = *(const float4*)&P[(size_t)(k0 + kl) * N_U + u0 + ul4];
      Pt[kl][ul4 + 0] = pv.x; Pt[kl][ul4 + 1] = pv.y;
      Pt[kl][ul4 + 2] = pv.z; Pt[kl][ul4 + 3] = pv.w;
      ss += pv.x * pv.x + pv.y * pv.y + pv.z * pv.z + pv.w * pv.w;
    }
  }
  __syncthreads();
  {
    const int k4 = (t & 15) * 4, ulb = t >> 4;
    #pragma unroll
    for (int pass = 0; pass < 4; ++pass) {
      int ul = ulb + pass * 16;
      float4 uv = *(const float4*)&U[(size_t)(u0 + ul) * KD + k0 + k4];
      ss += uv.x * uv.x + uv.y * uv.y + uv.z * uv.z + uv.w * uv.w;
      ushort4 w;
      w.x = f2bf(uv.x * Pt[k4 + 0][ul]);
      w.y = f2bf(uv.y * Pt[k4 + 1][ul]);
      w.z = f2bf(uv.z * Pt[k4 + 2][ul]);
      w.w = f2bf(uv.w * Pt[k4 + 3][ul]);
      *(ushort4*)&Abf[(size_t)(u0 + ul) * KD + k0 + k4] = w;
    }
  }
  block_reduce_store(ss, ws + REGA_BASE + blockIdx.y * 128 + blockIdx.x);
}

// V -> bf16; partial sum(V^2) to slot.
__global__ __launch_bounds__(256) void pack_v_kernel(
    const float* __restrict__ V, unsigned short* __restrict__ Vbf,
    float* __restrict__ ws)
{
  size_t i = ((size_t)blockIdx.x * 256 + threadIdx.x) * 4;
  float4 v = *(const float4*)&V[i];
  float ss = v.x * v.x + v.y * v.y + v.z * v.z + v.w * v.w;
  ushort4 w;
  w.x = f2bf(v.x); w.y = f2bf(v.y); w.z = f2bf(v.z); w.w = f2bf(v.w);
  *(ushort4*)&Vbf[i] = w;
  block_reduce_store(ss, ws + REGV_BASE + blockIdx.x);
}

// ---------------------------------------------------------------------------
// 256x256 tile, BK=64, 512 thr / 8 waves (2x4), m201-style 8-phase schedule.
// LDS: [A s0][A s1][B s0][B s1], 16384 shorts each = 128 KiB total.
// Swizzle: logical 16B-chunk cc of row r stored at physical cc^(r&7) (XOR
// involution; source pre-swizzled, GLD dest linear — rule-21 compliant).
// Fragment reads then spread 16 lanes over 8 bank-groups x 2 = conflict-free.
// Per K-tile: 4 phases {mh,ks}, each: 8 ds_read_b128 -> barrier ->
// setprio(1) 16 MFMA setprio(0) -> barrier. Tile t+1's 8 global_load_lds all
// issued at tile t phase 0; single vmcnt(0) at phase 3 (3 phases of slack).
// ---------------------------------------------------------------------------
__global__ __launch_bounds__(512, 2) void gemm_loss_kernel(
    const float* __restrict__ R, const unsigned short* __restrict__ Abf,
    const unsigned short* __restrict__ Vbf, float* __restrict__ ws)
{
  __shared__ __align__(16) unsigned short LDS[65536];   // 128 KiB
  const int tid = threadIdx.x;
  const int wv = tid >> 6, lane = tid & 63;
  const int bid = blockIdx.x;
  const int tile = (bid & 7) * 128 + (bid >> 3);   // bijective XCD swizzle
  const int brow = tile >> 5, bcol = tile & 31;
  const int wr = wv >> 2, wc = wv & 3;             // 2 x 4 wave grid
  const int r0 = lane & 15, q = lane >> 4;

  f32x4 acc[8][4] = {};

  const unsigned short* Ag = Abf + (size_t)brow * 256 * KD;
  const unsigned short* Bg = Vbf + (size_t)bcol * 256 * KD;

// stage chunk c (0..1023 via tid, tid+512) of half h of one matrix:
// dest linear = matbase + s*16384 + h*8192 + c*8 shorts; src col-chunk
// pre-swizzled: cc = (c&7) ^ ((c>>3)&7).
#define STG(g, matbase, h, s, kt, c) \
  GLD16((g) + (size_t)((h) * 128 + ((c) >> 3)) * KD + (kt) + ((((c) & 7) ^ (((c) >> 3) & 7)) * 8), \
        &LDS[(matbase) + (s) * 16384 + (h) * 8192 + (size_t)(c) * 8])

#define STAGE_TILE(s, kt) do { \
    STG(Ag, 0, 0, s, kt, tid); STG(Ag, 0, 0, s, kt, tid + 512); \
    STG(Ag, 0, 1, s, kt, tid); STG(Ag, 0, 1, s, kt, tid + 512); \
    STG(Bg, 32768, 0, s, kt, tid); STG(Bg, 32768, 0, s, kt, tid + 512); \
    STG(Bg, 32768, 1, s, kt, tid); STG(Bg, 32768, 1, s, kt, tid + 512); \
  } while (0)

// one phase: 8 ds_read_b128 + (optional stage burst / vmcnt) + barrier pair
// around 16 MFMA. DO_X hooks run after the ds_reads, before the first barrier.
#define PHASE(s, mh, ks, DO_X) { \
    short8 a[4], b[4]; \
    const int ccb = (((q) + (ks) * 4) ^ (r0 & 7)) * 8; \
    _Pragma("unroll") for (int m = 0; m < 4; ++m) \
      a[m] = *(const short8*)&LDS[(s) * 16384 + ((wr * 128 + (mh) * 64 + m * 16 + r0) * 64) + ccb]; \
    _Pragma("unroll") for (int n = 0; n < 4; ++n) \
      b[n] = *(const short8*)&LDS[32768 + (s) * 16384 + ((wc * 64 + n * 16 + r0) * 64) + ccb]; \
    DO_X; \
    __builtin_amdgcn_s_barrier(); \
    __builtin_amdgcn_s_setprio(1); \
    _Pragma("unroll") for (int m = 0; m < 4; ++m) \
      _Pragma("unroll") for (int n = 0; n < 4; ++n) \
        acc[(mh) * 4 + m][n] = __builtin_amdgcn_mfma_f32_16x16x32_bf16(b[n], a[m], acc[(mh) * 4 + m][n], 0, 0, 0); \
    __builtin_amdgcn_s_setprio(0); \
    __builtin_amdgcn_s_barrier(); \
  }

#define VMDRAIN asm volatile("s_waitcnt vmcnt(0)" ::: "memory")

  // prologue: stage K-tile 0 into slot 0.
  STAGE_TILE(0, 0);
  VMDRAIN;
  __builtin_amdgcn_s_barrier();

  #pragma unroll
  for (int t = 0; t < 4; ++t) {
    const int s = t & 1;
    if (t < 3) {
      PHASE(s, 0, 0, STAGE_TILE(s ^ 1, (t + 1) * 64));
      PHASE(s, 1, 0, );
      PHASE(s, 0, 1, );
      PHASE(s, 1, 1, VMDRAIN);
    } else {
      PHASE(s, 0, 0, );
      PHASE(s, 1, 0, );
      PHASE(s, 0, 1, );
      PHASE(s, 1, 1, );
    }
  }
#undef PHASE
#undef STAGE_TILE
#undef STG

  // Epilogue (R6-verified swapped-operand mapping):
  //   pred_row = brow*256 + wr*128 + M*16 + (lane&15)      (M = mh*4+m)
  //   pred_col = bcol*256 + wc*64  + n*16 + (lane>>4)*4 + j
  // M-pairs: 8 float4 R loads in flight per batch (VGPR-bounded MLP).
  float lsum = 0.f;
  const int row0 = brow * 256 + wr * 128 + r0;
  const size_t col0 = (size_t)bcol * 256 + wc * 64 + q * 4;
  #pragma unroll
  for (int mp = 0; mp < 4; ++mp) {
    float4 rv[2][4];
    #pragma unroll
    for (int h = 0; h < 2; ++h) {
      const float* rp = R + (size_t)(row0 + (mp * 2 + h) * 16) * N_I + col0;
      #pragma unroll
      for (int n = 0; n < 4; ++n) rv[h][n] = *(const float4*)&rp[n * 16];
    }
    #pragma unroll
    for (int h = 0; h < 2; ++h) {
      const int M = mp * 2 + h;
      #pragma unroll
      for (int n = 0; n < 4; ++n) {
        if (rv[h][n].x != 0.f) { float d = rv[h][n].x - acc[M][n][0]; lsum += d * d; }
        if (rv[h][n].y != 0.f) { float d = rv[h][n].y - acc[M][n][1]; lsum += d * d; }
        if (rv[h][n].z != 0.f) { float d = rv[h][n].z - acc[M][n][2]; lsum += d * d; }
        if (rv[h][n].w != 0.f) { float d = rv[h][n].w - acc[M][n][3]; lsum += d * d; }
      }
    }
  }

  // per-wave reduce + per-wave slot store.
  #pragma unroll
  for (int off = 32; off > 0; off >>= 1) lsum += __shfl_down(lsum, off, 64);
  if (lane == 0) ws[bid * 8 + wv] = lsum;
}

// Reduce all slots: out = err/2 + 0.1/2 * regsum.
__global__ __launch_bounds__(256) void finalize_kernel(
    const float* __restrict__ ws, float* __restrict__ out)
{
  __shared__ float sh[256];
  const int tid = threadIdx.x;
  float e = 0.f, r = 0.f;
  for (int i = tid; i < ERR_SLOTS; i += 256) e += ws[i];
  for (int i = REGA_BASE + tid; i < SLOTS_END; i += 256) r += ws[i];
  sh[tid] = 0.5f * e + 0.05f * r;
  __syncthreads();
  #pragma unroll
  for (int s = 128; s > 0; s >>= 1) {
    if (tid < s) sh[tid] += sh[tid + s];
    __syncthreads();
  }
  if (tid == 0) out[0] = sh[0];
}

extern "C" void kernel_launch(void* const* d_in, const int* in_sizes, int n_in,
                              void* d_out, int out_size, void* d_ws, size_t ws_size,
                              hipStream_t stream) {
  const float* R = (const float*)d_in[0];
  const float* U = (const float*)d_in[1];
  const float* V = (const float*)d_in[2];
  // d_in[3]=alpha, d_in[4]=Y, d_in[6]=Q: dead w.r.t. the returned value.
  const float* P = (const float*)d_in[5];

  float* ws = (float*)d_ws;                                           // slots
  unsigned short* Abf = (unsigned short*)((char*)d_ws + (1 << 20));   // 4 MiB
  unsigned short* Vbf = Abf + (size_t)N_U * KD;                       // 4 MiB
  float* out = (float*)d_out;

  pack_a_kernel<<<dim3(N_U / 64, KD / 64), 256, 0, stream>>>(U, P, Abf, ws);
  pack_v_kernel<<<dim3((N_I * KD) / (256 * 4)), 256, 0, stream>>>(V, Vbf, ws);
  gemm_loss_kernel<<<1024, 512, 0, stream>>>(R, Abf, Vbf, ws);
  finalize_kernel<<<1, 256, 0, stream>>>(ws, out);
}